// Round 1
// baseline (1350.265 us; speedup 1.0000x reference)
//
#include <hip/hip_runtime.h>
#include <math.h>

#define N_TOKENS 262144
#define D_MODEL  1024

// ---------------------------------------------------------------------------
// Kernel 1: scores[row] = dot(x[row,:], W) + b    (memory-bound, 1.07 GB read)
// One wave (64 lanes) per row. Lane l covers float4 indices l, l+64, l+128,
// l+192 of the 256-float4 row -> fully coalesced 1KB-per-instruction loads.
// W (4KB) is held in 16 registers per lane, loaded once per wave.
// ---------------------------------------------------------------------------
__global__ __launch_bounds__(256) void ema_matvec_kernel(
    const float* __restrict__ x,
    const float* __restrict__ W,
    const float* __restrict__ b,
    float* __restrict__ scores)
{
    const int lane = threadIdx.x & 63;
    const int wave_in_block = threadIdx.x >> 6;
    const int wave_id = blockIdx.x * 4 + wave_in_block;
    const int n_waves = gridDim.x * 4;

    const float4* W4 = (const float4*)W;
    const float4 w0 = W4[lane];
    const float4 w1 = W4[lane + 64];
    const float4 w2 = W4[lane + 128];
    const float4 w3 = W4[lane + 192];
    const float b0 = b[0];

    for (int row = wave_id; row < N_TOKENS; row += n_waves) {
        const float4* X4 = (const float4*)(x + (size_t)row * D_MODEL);
        const float4 x0 = X4[lane];
        const float4 x1 = X4[lane + 64];
        const float4 x2 = X4[lane + 128];
        const float4 x3 = X4[lane + 192];

        float acc = x0.x * w0.x + x0.y * w0.y + x0.z * w0.z + x0.w * w0.w;
        acc += x1.x * w1.x + x1.y * w1.y + x1.z * w1.z + x1.w * w1.w;
        acc += x2.x * w2.x + x2.y * w2.y + x2.z * w2.z + x2.w * w2.w;
        acc += x3.x * w3.x + x3.y * w3.y + x3.z * w3.z + x3.w * w3.w;

        // 64-lane butterfly reduction
        #pragma unroll
        for (int off = 32; off > 0; off >>= 1)
            acc += __shfl_xor(acc, off, 64);

        if (lane == 0) scores[row] = acc + b0;
    }
}

// ---------------------------------------------------------------------------
// Kernel 2: EMA recurrence + per-block max.
// ema_j = 0.5*s_j + 0.5*ema_{j-1}. Influence decays as 2^-(j-i), so a 64-score
// halo makes each 128-score segment computable independently to ~2^-64 error
// (threshold is 5.5e-2). 2048 threads total, segments tile N exactly.
// ---------------------------------------------------------------------------
#define SEG   128
#define HALO  64
#define EMA_BLOCKS 8   // 8 blocks * 256 threads * SEG = 262144

__global__ __launch_bounds__(256) void ema_scan_kernel(
    const float* __restrict__ scores,
    float* __restrict__ block_max)
{
    const int t = blockIdx.x * blockDim.x + threadIdx.x;
    const int start = t * SEG;
    int p = start - HALO;
    if (p < 0) p = 0;

    float ema = 0.0f;
    for (int i = p; i < start; ++i)
        ema = 0.5f * scores[i] + 0.5f * ema;

    float m = -INFINITY;
    const int end = start + SEG;
    for (int i = start; i < end; ++i) {
        ema = 0.5f * scores[i] + 0.5f * ema;
        m = fmaxf(m, ema);
    }

    // wave max
    #pragma unroll
    for (int off = 32; off > 0; off >>= 1)
        m = fmaxf(m, __shfl_xor(m, off, 64));

    __shared__ float smax[4];
    if ((threadIdx.x & 63) == 0) smax[threadIdx.x >> 6] = m;
    __syncthreads();
    if (threadIdx.x == 0) {
        float r = fmaxf(fmaxf(smax[0], smax[1]), fmaxf(smax[2], smax[3]));
        block_max[blockIdx.x] = r;
    }
}

// ---------------------------------------------------------------------------
// Kernel 3: reduce the 8 block maxima -> d_out[0]
// ---------------------------------------------------------------------------
__global__ void ema_final_kernel(const float* __restrict__ block_max,
                                 float* __restrict__ out)
{
    float m = -INFINITY;
    if (threadIdx.x < EMA_BLOCKS) m = block_max[threadIdx.x];
    #pragma unroll
    for (int off = 32; off > 0; off >>= 1)
        m = fmaxf(m, __shfl_xor(m, off, 64));
    if (threadIdx.x == 0) out[0] = m;
}

extern "C" void kernel_launch(void* const* d_in, const int* in_sizes, int n_in,
                              void* d_out, int out_size, void* d_ws, size_t ws_size,
                              hipStream_t stream) {
    const float* x = (const float*)d_in[0];
    const float* W = (const float*)d_in[1];
    const float* b = (const float*)d_in[2];
    float* out = (float*)d_out;

    float* scores    = (float*)d_ws;              // N_TOKENS floats (1 MB)
    float* block_max = scores + N_TOKENS;         // EMA_BLOCKS floats

    ema_matvec_kernel<<<4096, 256, 0, stream>>>(x, W, b, scores);
    ema_scan_kernel<<<EMA_BLOCKS, 256, 0, stream>>>(scores, block_max);
    ema_final_kernel<<<1, 64, 0, stream>>>(block_max, out);
}